// Round 1
// baseline (1566.185 us; speedup 1.0000x reference)
//
#include <hip/hip_runtime.h>
#include <hip/hip_bf16.h>
#include <math.h>

// Problem constants (B=1)
#define NTOK 8192
#define DIM  1024
#define HDIM 512
#define KTOP 100
#define CHUNK 1024
#define KTH_RANK 2457   // threshold = 2457th-largest of Acmb == sort_asc[5735]

// ---- monotone float<->uint key (order-preserving) ----
__device__ __forceinline__ unsigned key_of(float f) {
  unsigned u = __float_as_uint(f);
  return (u & 0x80000000u) ? ~u : (u | 0x80000000u);
}
__device__ __forceinline__ float float_of_key(unsigned key) {
  unsigned u = (key & 0x80000000u) ? (key ^ 0x80000000u) : ~key;
  return __uint_as_float(u);
}

// ============================================================
// GEMM NN + bias + tanh: C[m,n] = tanh(sum_k A[m,k]*W[k,n] + b[n])
// 64x64 tile, block 256, 4x4 per thread, k-chunk 32.
// LDS tiles stored [k][m]/[k][n] so fragments are ds_read_b128.
// ============================================================
__global__ __launch_bounds__(256) void gemm_nn_bias_tanh(
    const float* __restrict__ A, const float* __restrict__ W,
    const float* __restrict__ bias, float* __restrict__ C,
    int M, int Nc, int Kc)
{
  __shared__ float As[32][68];  // [k][m], pad 68 keeps float4 align + spreads banks
  __shared__ float Bs[32][68];  // [k][n]
  const int tid = threadIdx.x;
  const int tx = tid & 15, ty = tid >> 4;
  const int bm = blockIdx.y * 64, bn = blockIdx.x * 64;
  float acc[4][4] = {};
  for (int k0 = 0; k0 < Kc; k0 += 32) {
#pragma unroll
    for (int it = 0; it < 2; ++it) {            // A tile 64 rows x 32 k
      int f4 = tid + it * 256;
      int r = f4 >> 3, c4 = (f4 & 7) << 2;
      float4 v = *(const float4*)&A[(size_t)(bm + r) * Kc + k0 + c4];
      As[c4 + 0][r] = v.x; As[c4 + 1][r] = v.y; As[c4 + 2][r] = v.z; As[c4 + 3][r] = v.w;
    }
#pragma unroll
    for (int it = 0; it < 2; ++it) {            // W tile 32 k x 64 n
      int f4 = tid + it * 256;
      int r = f4 >> 4, c4 = (f4 & 15) << 2;
      float4 v = *(const float4*)&W[(size_t)(k0 + r) * Nc + bn + c4];
      *(float4*)&Bs[r][c4] = v;
    }
    __syncthreads();
#pragma unroll
    for (int kk = 0; kk < 32; ++kk) {
      float4 a4 = *(const float4*)&As[kk][ty << 2];
      float4 b4 = *(const float4*)&Bs[kk][tx << 2];
      float af[4] = {a4.x, a4.y, a4.z, a4.w};
      float bf[4] = {b4.x, b4.y, b4.z, b4.w};
#pragma unroll
      for (int i = 0; i < 4; ++i)
#pragma unroll
        for (int j = 0; j < 4; ++j)
          acc[i][j] = fmaf(af[i], bf[j], acc[i][j]);
    }
    __syncthreads();
  }
#pragma unroll
  for (int i = 0; i < 4; ++i) {
    int row = bm + (ty << 2) + i;
    float4 o;
    o.x = tanhf(acc[i][0] + bias[bn + (tx << 2) + 0]);
    o.y = tanhf(acc[i][1] + bias[bn + (tx << 2) + 1]);
    o.z = tanhf(acc[i][2] + bias[bn + (tx << 2) + 2]);
    o.w = tanhf(acc[i][3] + bias[bn + (tx << 2) + 3]);
    *(float4*)&C[(size_t)row * Nc + bn + (tx << 2)] = o;
  }
}

// ============================================================
// GEMM NT: C[m,n] = sum_k A[m,k]*B[n,k]   (A,B row-major along k)
// ============================================================
__global__ __launch_bounds__(256) void gemm_nt(
    const float* __restrict__ A, const float* __restrict__ B,
    float* __restrict__ C, int Kc, int ldc)
{
  __shared__ float As[32][68];  // [k][m]
  __shared__ float Bs[32][68];  // [k][n]
  const int tid = threadIdx.x;
  const int tx = tid & 15, ty = tid >> 4;
  const int bm = blockIdx.y * 64, bn = blockIdx.x * 64;
  float acc[4][4] = {};
  for (int k0 = 0; k0 < Kc; k0 += 32) {
#pragma unroll
    for (int it = 0; it < 2; ++it) {
      int f4 = tid + it * 256;
      int r = f4 >> 3, c4 = (f4 & 7) << 2;
      float4 v = *(const float4*)&A[(size_t)(bm + r) * Kc + k0 + c4];
      As[c4 + 0][r] = v.x; As[c4 + 1][r] = v.y; As[c4 + 2][r] = v.z; As[c4 + 3][r] = v.w;
    }
#pragma unroll
    for (int it = 0; it < 2; ++it) {
      int f4 = tid + it * 256;
      int r = f4 >> 3, c4 = (f4 & 7) << 2;
      float4 v = *(const float4*)&B[(size_t)(bn + r) * Kc + k0 + c4];
      Bs[c4 + 0][r] = v.x; Bs[c4 + 1][r] = v.y; Bs[c4 + 2][r] = v.z; Bs[c4 + 3][r] = v.w;
    }
    __syncthreads();
#pragma unroll
    for (int kk = 0; kk < 32; ++kk) {
      float4 a4 = *(const float4*)&As[kk][ty << 2];
      float4 b4 = *(const float4*)&Bs[kk][tx << 2];
      float af[4] = {a4.x, a4.y, a4.z, a4.w};
      float bf[4] = {b4.x, b4.y, b4.z, b4.w};
#pragma unroll
      for (int i = 0; i < 4; ++i)
#pragma unroll
        for (int j = 0; j < 4; ++j)
          acc[i][j] = fmaf(af[i], bf[j], acc[i][j]);
    }
    __syncthreads();
  }
#pragma unroll
  for (int i = 0; i < 4; ++i) {
    int row = bm + (ty << 2) + i;
    float4 o = make_float4(acc[i][0], acc[i][1], acc[i][2], acc[i][3]);
    *(float4*)&C[(size_t)row * ldc + bn + (tx << 2)] = o;
  }
}

// ============================================================
// Row L2-normalize: dst[r,:] = src[r,:] / max(||src[r,:]||, 1e-12)
// one wave per row (HDIM=512 -> 8 floats/lane)
// ============================================================
__global__ __launch_bounds__(256) void rownorm(
    const float* __restrict__ src, float* __restrict__ dst)
{
  const int lane = threadIdx.x & 63;
  const int row = blockIdx.x * 4 + (threadIdx.x >> 6);
  const float* s = src + (size_t)row * HDIM;
  float4 v0 = *(const float4*)&s[lane * 8];
  float4 v1 = *(const float4*)&s[lane * 8 + 4];
  float ss = v0.x*v0.x + v0.y*v0.y + v0.z*v0.z + v0.w*v0.w
           + v1.x*v1.x + v1.y*v1.y + v1.z*v1.z + v1.w*v1.w;
#pragma unroll
  for (int off = 32; off > 0; off >>= 1) ss += __shfl_xor(ss, off);
  float sc = 1.0f / fmaxf(sqrtf(ss), 1e-12f);
  float* d = dst + (size_t)row * HDIM;
  float4 o0 = make_float4(v0.x*sc, v0.y*sc, v0.z*sc, v0.w*sc);
  float4 o1 = make_float4(v1.x*sc, v1.y*sc, v1.z*sc, v1.w*sc);
  *(float4*)&d[lane * 8]     = o0;
  *(float4*)&d[lane * 8 + 4] = o1;
}

// ============================================================
// Per-row exact top-100 (4-pass byte radix select in LDS) ->
// sort 100 ascending -> Acmb[row] = -(A1.Wa1 + A1^2.Wa2 + b)
// one block (256 thr) per row
// ============================================================
__global__ __launch_bounds__(256) void topk_acmb(
    const float* __restrict__ Arows, const float* __restrict__ WA_w,
    const float* __restrict__ WA_b, float* __restrict__ Acmb, int row_base)
{
  __shared__ float rowv[NTOK];
  __shared__ unsigned hist[256];
  __shared__ unsigned sufs[256];
  __shared__ float cand[128];
  __shared__ float red[128];
  __shared__ unsigned s_prefix, s_need, s_cnt, s_cnt2;

  const int tid = threadIdx.x;
  const float* src = Arows + (size_t)blockIdx.x * NTOK;
#pragma unroll
  for (int it = 0; it < 8; ++it) {
    int i = tid + it * 256;
    float4 v = ((const float4*)src)[i];
    *(float4*)&rowv[i * 4] = v;
  }
  if (tid == 0) { s_prefix = 0u; s_need = KTOP; s_cnt = 0u; s_cnt2 = 0u; }
  __syncthreads();

  // ---- 4-pass radix select of the 100th-largest key ----
  for (int pass = 3; pass >= 0; --pass) {
    hist[tid] = 0u;
    __syncthreads();
    unsigned pref  = s_prefix;
    unsigned pmask = (pass == 3) ? 0u : (0xFFFFFFFFu << ((pass + 1) * 8));
    for (int it = 0; it < 32; ++it) {
      unsigned key = key_of(rowv[tid + it * 256]);
      if ((key & pmask) == pref)
        atomicAdd(&hist[(key >> (pass * 8)) & 255u], 1u);
    }
    __syncthreads();
    sufs[tid] = hist[tid];
    __syncthreads();
    for (int off = 1; off < 256; off <<= 1) {   // suffix-sum scan
      unsigned add = (tid + off < 256) ? sufs[tid + off] : 0u;
      __syncthreads();
      sufs[tid] += add;
      __syncthreads();
    }
    unsigned need = s_need;
    __syncthreads();
    unsigned above = (tid == 255) ? 0u : sufs[tid + 1];
    if (sufs[tid] >= need && above < need) {    // unique boundary digit
      s_prefix = pref | ((unsigned)tid << (pass * 8));
      s_need   = need - above;
    }
    __syncthreads();
  }
  const unsigned kth    = s_prefix;  // exact key of 100th largest
  const unsigned needEq = s_need;    // how many equal-to-kth to take

  // ---- collect: strictly-greater then equals ----
  if (tid < 128) cand[tid] = -2.0f;  // below min possible (|A|<=1)
  __syncthreads();
  for (int it = 0; it < 32; ++it) {
    float v = rowv[tid + it * 256];
    if (key_of(v) > kth) cand[atomicAdd(&s_cnt, 1u)] = v;
  }
  __syncthreads();
  const unsigned nAbove = s_cnt;     // == KTOP - needEq
  for (int it = 0; it < 32; ++it) {
    float v = rowv[tid + it * 256];
    if (key_of(v) == kth) {
      unsigned p = atomicAdd(&s_cnt2, 1u);
      if (p < needEq) cand[nAbove + p] = v;
    }
  }
  __syncthreads();

  // ---- bitonic sort 128 ascending (pads sink to front) ----
  for (int k = 2; k <= 128; k <<= 1)
    for (int j = k >> 1; j > 0; j >>= 1) {
      if (tid < 128) {
        int i = tid, ixj = i ^ j;
        if (ixj > i) {
          float a = cand[i], b = cand[ixj];
          if ((a > b) == ((i & k) == 0)) { cand[i] = b; cand[ixj] = a; }
        }
      }
      __syncthreads();
    }

  // ---- Acmb = -(sum A1[i]*w1[i] + A1[i]^2*w2[i] + b) ----
  float term = 0.0f;
  if (tid < KTOP) {
    float a1 = cand[28 + tid];       // indices 28..127 = top-100 ascending
    term = a1 * WA_w[tid] + a1 * a1 * WA_w[KTOP + tid];
  }
  if (tid < 128) red[tid] = term;
  __syncthreads();
  for (int off = 64; off > 0; off >>= 1) {
    if (tid < off) red[tid] += red[tid + off];
    __syncthreads();
  }
  if (tid == 0) Acmb[row_base + (int)blockIdx.x] = -(red[0] + WA_b[0]);
}

// ============================================================
// Threshold (rank select) + softmax over all N, writes Aw to out[1..N]
// single block of 1024
// ============================================================
__global__ __launch_bounds__(1024) void thr_softmax(
    const float* __restrict__ Acmb, float* __restrict__ out)
{
  __shared__ float vals[NTOK];
  __shared__ unsigned hist[256];
  __shared__ unsigned sufs[256];
  __shared__ float red[1024];
  __shared__ unsigned s_prefix, s_need;
  const int tid = threadIdx.x;
#pragma unroll
  for (int s = 0; s < 8; ++s) vals[tid + s * 1024] = Acmb[tid + s * 1024];
  if (tid == 0) { s_prefix = 0u; s_need = KTH_RANK; }
  __syncthreads();

  for (int pass = 3; pass >= 0; --pass) {
    if (tid < 256) hist[tid] = 0u;
    __syncthreads();
    unsigned pref  = s_prefix;
    unsigned pmask = (pass == 3) ? 0u : (0xFFFFFFFFu << ((pass + 1) * 8));
#pragma unroll
    for (int s = 0; s < 8; ++s) {
      unsigned key = key_of(vals[tid + s * 1024]);
      if ((key & pmask) == pref)
        atomicAdd(&hist[(key >> (pass * 8)) & 255u], 1u);
    }
    __syncthreads();
    if (tid < 256) sufs[tid] = hist[tid];
    __syncthreads();
    for (int off = 1; off < 256; off <<= 1) {
      unsigned add = 0u;
      if (tid < 256 && tid + off < 256) add = sufs[tid + off];
      __syncthreads();
      if (tid < 256) sufs[tid] += add;
      __syncthreads();
    }
    unsigned need = s_need;
    __syncthreads();
    if (tid < 256) {
      unsigned above = (tid == 255) ? 0u : sufs[tid + 1];
      if (sufs[tid] >= need && above < need) {
        s_prefix = pref | ((unsigned)tid << (pass * 8));
        s_need   = need - above;
      }
    }
    __syncthreads();
  }
  const float thre = float_of_key(s_prefix);

  float loc[8]; float mx = -1e30f;
#pragma unroll
  for (int s = 0; s < 8; ++s) {
    float v = vals[tid + s * 1024];
    v = (v > thre) ? v : 0.0f;        // strict >, zeros participate
    loc[s] = v; mx = fmaxf(mx, v);
  }
  red[tid] = mx; __syncthreads();
  for (int off = 512; off > 0; off >>= 1) {
    if (tid < off) red[tid] = fmaxf(red[tid], red[tid + off]);
    __syncthreads();
  }
  float m = red[0]; __syncthreads();
  float sm = 0.0f;
#pragma unroll
  for (int s = 0; s < 8; ++s) sm += expf(loc[s] - m);
  red[tid] = sm; __syncthreads();
  for (int off = 512; off > 0; off >>= 1) {
    if (tid < off) red[tid] += red[tid + off];
    __syncthreads();
  }
  float Z = red[0];
#pragma unroll
  for (int s = 0; s < 8; ++s)
    out[1 + tid + s * 1024] = expf(loc[s] - m) / Z;
}

// ============================================================
// z partials: zpart[g, h] = sum_{n in block g} Aw[n] * query[n, h]
// ============================================================
__global__ __launch_bounds__(256) void z_partial(
    const float* __restrict__ aw, const float* __restrict__ query,
    float* __restrict__ zpart)
{
  const int g = blockIdx.x, t = threadIdx.x;
  float a0 = 0.f, a1 = 0.f;
  for (int r = 0; r < 64; ++r) {
    int n = g * 64 + r;
    float w = aw[n];
    const float* q = query + (size_t)n * HDIM;
    a0 = fmaf(w, q[t],       a0);
    a1 = fmaf(w, q[t + 256], a1);
  }
  zpart[(size_t)g * HDIM + t]       = a0;
  zpart[(size_t)g * HDIM + t + 256] = a1;
}

// Y_prob = sum_h z[h]*cls_w[h] + cls_b  (deterministic tree)
__global__ __launch_bounds__(512) void finalize(
    const float* __restrict__ zpart, const float* __restrict__ cls_w,
    const float* __restrict__ cls_b, float* __restrict__ out)
{
  __shared__ float red[512];
  const int t = threadIdx.x;
  float s = 0.f;
  for (int g = 0; g < 128; ++g) s += zpart[(size_t)g * HDIM + t];
  red[t] = s * cls_w[t];
  __syncthreads();
  for (int off = 256; off > 0; off >>= 1) {
    if (t < off) red[t] += red[t + off];
    __syncthreads();
  }
  if (t == 0) out[0] = red[0] + cls_b[0];
}

// ============================================================
extern "C" void kernel_launch(void* const* d_in, const int* in_sizes, int n_in,
                              void* d_out, int out_size, void* d_ws, size_t ws_size,
                              hipStream_t stream) {
  (void)in_sizes; (void)n_in; (void)out_size; (void)ws_size;
  const float* x_q   = (const float*)d_in[0];
  const float* x_k   = (const float*)d_in[1];
  const float* WQ_w  = (const float*)d_in[2];
  const float* WQ_b  = (const float*)d_in[3];
  const float* WK_w  = (const float*)d_in[4];
  const float* WK_b  = (const float*)d_in[5];
  const float* WA_w  = (const float*)d_in[6];
  const float* WA_b  = (const float*)d_in[7];
  const float* cls_w = (const float*)d_in[8];
  const float* cls_b = (const float*)d_in[9];
  float* out = (float*)d_out;
  float* ws  = (float*)d_ws;

  // workspace layout (floats): total ~21.05M floats ~= 80.3 MB
  float* query = ws;                    // 8192*512
  float* qn    = ws + 4194304;          // 8192*512
  float* kn    = ws + 8388608;          // 8192*512 (keyt, then normalized in place)
  float* Acmb  = ws + 12582912;         // 8192
  float* zpart = ws + 12591104;         // 128*512
  float* Ach   = ws + 12656640;         // CHUNK*8192 = 8388608

  dim3 b256(256);
  // projections + tanh
  gemm_nn_bias_tanh<<<dim3(HDIM/64, NTOK/64), b256, 0, stream>>>(x_q, WQ_w, WQ_b, query, NTOK, HDIM, DIM);
  gemm_nn_bias_tanh<<<dim3(HDIM/64, NTOK/64), b256, 0, stream>>>(x_k, WK_w, WK_b, kn,    NTOK, HDIM, DIM);
  // normalize
  rownorm<<<NTOK/4, b256, 0, stream>>>(query, qn);
  rownorm<<<NTOK/4, b256, 0, stream>>>(kn, kn);
  // A = qn . kn^T in row chunks, fused exact top-100 -> Acmb
  for (int c = 0; c < NTOK / CHUNK; ++c) {
    gemm_nt<<<dim3(NTOK/64, CHUNK/64), b256, 0, stream>>>(qn + (size_t)c * CHUNK * HDIM, kn, Ach, HDIM, NTOK);
    topk_acmb<<<CHUNK, b256, 0, stream>>>(Ach, WA_w, WA_b, Acmb, c * CHUNK);
  }
  // threshold + softmax -> Aw (out[1..8192])
  thr_softmax<<<1, 1024, 0, stream>>>(Acmb, out);
  // z = Aw @ query ; Y = z.cls_w + cls_b -> out[0]
  z_partial<<<128, b256, 0, stream>>>(out + 1, query, zpart);
  finalize<<<1, 512, 0, stream>>>(zpart, cls_w, cls_b, out);
}

// Round 3
// 766.146 us; speedup vs baseline: 2.0442x; 2.0442x over previous
//
#include <hip/hip_runtime.h>
#include <hip/hip_bf16.h>
#include <math.h>

#define NTOK 8192
#define DIM  1024
#define HDIM 512
#define KTOP 100
#define CHUNK 1024
#define KTH_RANK 2457   // threshold = 2457th-largest of Acmb == sort_asc[5735]

typedef float f32x4 __attribute__((ext_vector_type(4)));
typedef short bf16x8 __attribute__((ext_vector_type(8)));
typedef unsigned int u32;
typedef unsigned short u16;

// ---- monotone float<->uint key (order-preserving) ----
__device__ __forceinline__ unsigned key_of(float f) {
  unsigned u = __float_as_uint(f);
  return (u & 0x80000000u) ? ~u : (u | 0x80000000u);
}
__device__ __forceinline__ float float_of_key(unsigned key) {
  unsigned u = (key & 0x80000000u) ? (key ^ 0x80000000u) : ~key;
  return __uint_as_float(u);
}
// ---- bf16 round-to-nearest-even helpers (bit level, deterministic) ----
__device__ __forceinline__ u16 bf16_rn(float x) {
  unsigned u = __float_as_uint(x);
  return (u16)((u + 0x7FFFu + ((u >> 16) & 1u)) >> 16);
}
__device__ __forceinline__ float bf16f(u16 h) {
  return __uint_as_float(((unsigned)h) << 16);
}
// ---- async global->LDS 16B (wave-uniform LDS base, per-lane global src) ----
__device__ __forceinline__ void gload16(const void* gptr, void* lptr) {
  __builtin_amdgcn_global_load_lds(
      (const __attribute__((address_space(1))) u32*)gptr,
      (__attribute__((address_space(3))) u32*)lptr, 16, 0, 0);
}

// shared MFMA inner block: 64x64 per wave, 4x4 frags of 16x16x32, 3-term split
__device__ __forceinline__ void mfma_step(const short* sAh, const short* sAl,
                                          const short* sBh, const short* sBl,
                                          int lane, int wm, int wn, f32x4 acc[4][4])
{
  bf16x8 ah[4], al[4];
#pragma unroll
  for (int m = 0; m < 4; ++m) {
    int off = (wm * 64 + m * 16 + (lane & 15)) * 32 + (lane >> 4) * 8;
    ah[m] = *(const bf16x8*)&sAh[off];
    al[m] = *(const bf16x8*)&sAl[off];
  }
#pragma unroll
  for (int n = 0; n < 4; ++n) {
    int off = (wn * 64 + n * 16 + (lane & 15)) * 32 + (lane >> 4) * 8;
    bf16x8 bh = *(const bf16x8*)&sBh[off];
    bf16x8 bl = *(const bf16x8*)&sBl[off];
#pragma unroll
    for (int m = 0; m < 4; ++m) {
      acc[m][n] = __builtin_amdgcn_mfma_f32_16x16x32_bf16(ah[m], bh, acc[m][n], 0, 0, 0);
      acc[m][n] = __builtin_amdgcn_mfma_f32_16x16x32_bf16(ah[m], bl, acc[m][n], 0, 0, 0);
      acc[m][n] = __builtin_amdgcn_mfma_f32_16x16x32_bf16(al[m], bh, acc[m][n], 0, 0, 0);
    }
  }
}

// ============================================================
// A-GEMM (NT): C[m,n] = sum_k (Ahi+Alo)[m,k] * (Bhi+Blo)[n,k]
// A,B bf16 hi/lo pairs, row-major along k. 128x128 tile, BK=32.
// ============================================================
__global__ __launch_bounds__(256) void gemm_hl_nt(
    const u16* __restrict__ Ahi, const u16* __restrict__ Alo,
    const u16* __restrict__ Bhi, const u16* __restrict__ Blo,
    float* __restrict__ C, int K, int ldc)
{
  __shared__ __align__(16) short sAh[4096], sAl[4096], sBh[4096], sBl[4096];
  const int tid = threadIdx.x;
  const int lane = tid & 63, wave = tid >> 6;
  const int wm = wave >> 1, wn = wave & 1;
  const int bm = blockIdx.y * 128, bn = blockIdx.x * 128;
  f32x4 acc[4][4] = {};

  // per-wave staging assignment (NO pointer arrays: addrspacecast init is illegal)
  const u16* mysrc = (wave == 0) ? (Ahi + (size_t)bm * K)
                   : (wave == 1) ? (Alo + (size_t)bm * K)
                   : (wave == 2) ? (Bhi + (size_t)bn * K)
                                 : (Blo + (size_t)bn * K);
  short* mydst = (wave == 0) ? sAh : (wave == 1) ? sAl : (wave == 2) ? sBh : sBl;

  for (int k0 = 0; k0 < K; k0 += 32) {
    // stage my 8KB part: 8 x (64 lanes x 16B); LDS linear [row][32k] bf16
#pragma unroll
    for (int c = 0; c < 8; ++c) {
      int row = c * 16 + (lane >> 2);
      gload16(mysrc + (size_t)row * K + k0 + (lane & 3) * 8, mydst + c * 512);
    }
    __syncthreads();   // drains vmcnt(0)+lgkmcnt(0) then barrier
    mfma_step(sAh, sAl, sBh, sBl, lane, wm, wn, acc);
    __syncthreads();
  }
#pragma unroll
  for (int m = 0; m < 4; ++m) {
    int rbase = bm + wm * 64 + m * 16 + (lane >> 4) * 4;
#pragma unroll
    for (int n = 0; n < 4; ++n) {
      int col = bn + wn * 64 + n * 16 + (lane & 15);
#pragma unroll
      for (int r = 0; r < 4; ++r)
        C[(size_t)(rbase + r) * ldc + col] = acc[m][n][r];
    }
  }
}

// ============================================================
// Projection GEMM: C[m,n] = tanh(sum_k A[m,k]*(Whi+Wlo)[n,k] + bias[n])
// A fp32 (split to hi/lo in-register during staging), W transposed bf16.
// ============================================================
__global__ __launch_bounds__(256) void gemm_f32a_hl_tanh(
    const float* __restrict__ A, const u16* __restrict__ Bhi,
    const u16* __restrict__ Blo, const float* __restrict__ bias,
    float* __restrict__ C, int K, int ldc)
{
  __shared__ __align__(16) short sAh[4096], sAl[4096], sBh[4096], sBl[4096];
  const int tid = threadIdx.x;
  const int lane = tid & 63, wave = tid >> 6;
  const int wm = wave >> 1, wn = wave & 1;
  const int bm = blockIdx.y * 128, bn = blockIdx.x * 128;
  f32x4 acc[4][4] = {};

  const u16* bs = (wave < 2) ? Bhi : Blo;
  short* bd = (wave < 2) ? sBh : sBl;
  const int cbase = (wave & 1) * 4;
  const int ar = tid >> 1, ak = (tid & 1) * 16;  // my 16-float slice of A tile

  for (int k0 = 0; k0 < K; k0 += 32) {
    // B: async stage my 4KB quarter
#pragma unroll
    for (int c = 0; c < 4; ++c) {
      int ch = cbase + c;
      int row = ch * 16 + (lane >> 2);
      gload16(bs + (size_t)(bn + row) * K + k0 + (lane & 3) * 8, bd + ch * 512);
    }
    // A: fp32 -> hi/lo bf16 in-register -> ds_write
    const float* ga = A + (size_t)(bm + ar) * K + k0 + ak;
    float f[16];
    *(float4*)&f[0]  = *(const float4*)ga;
    *(float4*)&f[4]  = *(const float4*)(ga + 4);
    *(float4*)&f[8]  = *(const float4*)(ga + 8);
    *(float4*)&f[12] = *(const float4*)(ga + 12);
    bf16x8 h0{}, h1{}, l0{}, l1{};
#pragma unroll
    for (int j = 0; j < 8; ++j) {
      u16 h = bf16_rn(f[j]);
      h0[j] = (short)h; l0[j] = (short)bf16_rn(f[j] - bf16f(h));
    }
#pragma unroll
    for (int j = 0; j < 8; ++j) {
      u16 h = bf16_rn(f[j + 8]);
      h1[j] = (short)h; l1[j] = (short)bf16_rn(f[j + 8] - bf16f(h));
    }
    *(bf16x8*)&sAh[ar * 32 + ak]     = h0;
    *(bf16x8*)&sAh[ar * 32 + ak + 8] = h1;
    *(bf16x8*)&sAl[ar * 32 + ak]     = l0;
    *(bf16x8*)&sAl[ar * 32 + ak + 8] = l1;
    __syncthreads();
    mfma_step(sAh, sAl, sBh, sBl, lane, wm, wn, acc);
    __syncthreads();
  }
#pragma unroll
  for (int m = 0; m < 4; ++m) {
    int rbase = bm + wm * 64 + m * 16 + (lane >> 4) * 4;
#pragma unroll
    for (int n = 0; n < 4; ++n) {
      int col = bn + wn * 64 + n * 16 + (lane & 15);
      float b = bias[col];
#pragma unroll
      for (int r = 0; r < 4; ++r)
        C[(size_t)(rbase + r) * ldc + col] = tanhf(acc[m][n][r] + b);
    }
  }
}

// ============================================================
// W [K=1024][N=512] fp32 -> WT hi/lo [512][1024] bf16 (tiled transpose)
// ============================================================
__global__ __launch_bounds__(256) void wt_cast(
    const float* __restrict__ W, u16* __restrict__ Thi, u16* __restrict__ Tlo)
{
  __shared__ float t[32][33];
  const int bx = blockIdx.x, by = blockIdx.y;       // n-block, k-block
  const int r = threadIdx.x >> 5, c = threadIdx.x & 31;
#pragma unroll
  for (int i = 0; i < 4; ++i)
    t[r + i * 8][c] = W[(size_t)(by * 32 + r + i * 8) * HDIM + bx * 32 + c];
  __syncthreads();
#pragma unroll
  for (int i = 0; i < 4; ++i) {
    int n = bx * 32 + r + i * 8, k = by * 32 + c;
    float v = t[c][r + i * 8];
    u16 h = bf16_rn(v);
    Thi[(size_t)n * DIM + k] = h;
    Tlo[(size_t)n * DIM + k] = bf16_rn(v - bf16f(h));
  }
}

// ============================================================
// Row L2-normalize fp32 src -> hi/lo bf16 (one wave per row)
// ============================================================
__global__ __launch_bounds__(256) void rownorm_split(
    const float* __restrict__ src, u16* __restrict__ hi, u16* __restrict__ lo)
{
  const int lane = threadIdx.x & 63;
  const int row = blockIdx.x * 4 + (threadIdx.x >> 6);
  const float* s = src + (size_t)row * HDIM;
  float4 v0 = *(const float4*)&s[lane * 8];
  float4 v1 = *(const float4*)&s[lane * 8 + 4];
  float ss = v0.x*v0.x + v0.y*v0.y + v0.z*v0.z + v0.w*v0.w
           + v1.x*v1.x + v1.y*v1.y + v1.z*v1.z + v1.w*v1.w;
#pragma unroll
  for (int off = 32; off > 0; off >>= 1) ss += __shfl_xor(ss, off);
  float sc = 1.0f / fmaxf(sqrtf(ss), 1e-12f);
  float q[8] = {v0.x*sc, v0.y*sc, v0.z*sc, v0.w*sc, v1.x*sc, v1.y*sc, v1.z*sc, v1.w*sc};
  u16 hh[8], ll[8];
#pragma unroll
  for (int j = 0; j < 8; ++j) { hh[j] = bf16_rn(q[j]); ll[j] = bf16_rn(q[j] - bf16f(hh[j])); }
  ushort4 ho0 = make_ushort4(hh[0], hh[1], hh[2], hh[3]);
  ushort4 ho1 = make_ushort4(hh[4], hh[5], hh[6], hh[7]);
  ushort4 lo0 = make_ushort4(ll[0], ll[1], ll[2], ll[3]);
  ushort4 lo1 = make_ushort4(ll[4], ll[5], ll[6], ll[7]);
  *(ushort4*)&hi[(size_t)row * HDIM + lane * 8]     = ho0;
  *(ushort4*)&hi[(size_t)row * HDIM + lane * 8 + 4] = ho1;
  *(ushort4*)&lo[(size_t)row * HDIM + lane * 8]     = lo0;
  *(ushort4*)&lo[(size_t)row * HDIM + lane * 8 + 4] = lo1;
}

// ============================================================
// Per-row exact top-100 (4-pass byte radix select on keys in LDS) ->
// sort 100 ascending -> Acmb[row]. One block (512 thr) per row.
// ============================================================
__global__ __launch_bounds__(512) void topk_acmb(
    const float* __restrict__ Arows, const float* __restrict__ WA_w,
    const float* __restrict__ WA_b, float* __restrict__ Acmb, int row_base)
{
  __shared__ unsigned rowk[NTOK];
  __shared__ unsigned hist[256];
  __shared__ unsigned sufs[256];
  __shared__ unsigned cand[128];
  __shared__ float red[128];
  __shared__ unsigned s_prefix, s_need, s_cnt, s_cnt2;

  const int tid = threadIdx.x;
  const float4* src = (const float4*)(Arows + (size_t)blockIdx.x * NTOK);
#pragma unroll
  for (int it = 0; it < 4; ++it) {
    int i = tid + it * 512;
    float4 v = src[i];
    uint4 kv = make_uint4(key_of(v.x), key_of(v.y), key_of(v.z), key_of(v.w));
    *(uint4*)&rowk[i * 4] = kv;
  }
  if (tid == 0) { s_prefix = 0u; s_need = KTOP; s_cnt = 0u; s_cnt2 = 0u; }
  __syncthreads();

  for (int pass = 3; pass >= 0; --pass) {
    if (tid < 256) hist[tid] = 0u;
    __syncthreads();
    unsigned pref  = s_prefix;
    unsigned pmask = (pass == 3) ? 0u : (0xFFFFFFFFu << ((pass + 1) * 8));
    for (int it = 0; it < 16; ++it) {
      unsigned key = rowk[tid + it * 512];
      if ((key & pmask) == pref)
        atomicAdd(&hist[(key >> (pass * 8)) & 255u], 1u);
    }
    __syncthreads();
    if (tid < 256) sufs[tid] = hist[tid];
    __syncthreads();
    for (int off = 1; off < 256; off <<= 1) {
      unsigned add = 0u;
      if (tid < 256 && tid + off < 256) add = sufs[tid + off];
      __syncthreads();
      if (tid < 256) sufs[tid] += add;
      __syncthreads();
    }
    unsigned need = s_need;
    __syncthreads();
    if (tid < 256) {
      unsigned above = (tid == 255) ? 0u : sufs[tid + 1];
      if (sufs[tid] >= need && above < need) {
        s_prefix = pref | ((unsigned)tid << (pass * 8));
        s_need   = need - above;
      }
    }
    __syncthreads();
  }
  const unsigned kth = s_prefix, needEq = s_need;

  if (tid < 128) cand[tid] = 0u;   // key 0 << any valid key, sinks to front
  __syncthreads();
  for (int it = 0; it < 16; ++it) {
    unsigned key = rowk[tid + it * 512];
    if (key > kth) cand[atomicAdd(&s_cnt, 1u)] = key;
  }
  __syncthreads();
  const unsigned nAbove = s_cnt;
  for (int it = 0; it < 16; ++it) {
    unsigned key = rowk[tid + it * 512];
    if (key == kth) {
      unsigned p = atomicAdd(&s_cnt2, 1u);
      if (p < needEq) cand[nAbove + p] = key;
    }
  }
  __syncthreads();

  for (int k = 2; k <= 128; k <<= 1)
    for (int j = k >> 1; j > 0; j >>= 1) {
      if (tid < 128) {
        int i = tid, ixj = i ^ j;
        if (ixj > i) {
          unsigned a = cand[i], b = cand[ixj];
          if ((a > b) == ((i & k) == 0)) { cand[i] = b; cand[ixj] = a; }
        }
      }
      __syncthreads();
    }

  float term = 0.0f;
  if (tid < KTOP) {
    float a1 = float_of_key(cand[28 + tid]);   // 28..127 = top-100 ascending
    term = a1 * WA_w[tid] + a1 * a1 * WA_w[KTOP + tid];
  }
  if (tid < 128) red[tid] = term;
  __syncthreads();
  for (int off = 64; off > 0; off >>= 1) {
    if (tid < off) red[tid] += red[tid + off];
    __syncthreads();
  }
  if (tid == 0) Acmb[row_base + (int)blockIdx.x] = -(red[0] + WA_b[0]);
}

// ============================================================
// Threshold (rank select) + softmax over N -> Aw in out[1..N]
// ============================================================
__global__ __launch_bounds__(1024) void thr_softmax(
    const float* __restrict__ Acmb, float* __restrict__ out)
{
  __shared__ float vals[NTOK];
  __shared__ unsigned hist[256];
  __shared__ unsigned sufs[256];
  __shared__ float red[1024];
  __shared__ unsigned s_prefix, s_need;
  const int tid = threadIdx.x;
#pragma unroll
  for (int s = 0; s < 8; ++s) vals[tid + s * 1024] = Acmb[tid + s * 1024];
  if (tid == 0) { s_prefix = 0u; s_need = KTH_RANK; }
  __syncthreads();

  for (int pass = 3; pass >= 0; --pass) {
    if (tid < 256) hist[tid] = 0u;
    __syncthreads();
    unsigned pref  = s_prefix;
    unsigned pmask = (pass == 3) ? 0u : (0xFFFFFFFFu << ((pass + 1) * 8));
#pragma unroll
    for (int s = 0; s < 8; ++s) {
      unsigned key = key_of(vals[tid + s * 1024]);
      if ((key & pmask) == pref)
        atomicAdd(&hist[(key >> (pass * 8)) & 255u], 1u);
    }
    __syncthreads();
    if (tid < 256) sufs[tid] = hist[tid];
    __syncthreads();
    for (int off = 1; off < 256; off <<= 1) {
      unsigned add = 0u;
      if (tid < 256 && tid + off < 256) add = sufs[tid + off];
      __syncthreads();
      if (tid < 256) sufs[tid] += add;
      __syncthreads();
    }
    unsigned need = s_need;
    __syncthreads();
    if (tid < 256) {
      unsigned above = (tid == 255) ? 0u : sufs[tid + 1];
      if (sufs[tid] >= need && above < need) {
        s_prefix = pref | ((unsigned)tid << (pass * 8));
        s_need   = need - above;
      }
    }
    __syncthreads();
  }
  const float thre = float_of_key(s_prefix);

  float loc[8]; float mx = -1e30f;
#pragma unroll
  for (int s = 0; s < 8; ++s) {
    float v = vals[tid + s * 1024];
    v = (v > thre) ? v : 0.0f;
    loc[s] = v; mx = fmaxf(mx, v);
  }
  red[tid] = mx; __syncthreads();
  for (int off = 512; off > 0; off >>= 1) {
    if (tid < off) red[tid] = fmaxf(red[tid], red[tid + off]);
    __syncthreads();
  }
  float m = red[0]; __syncthreads();
  float sm = 0.0f;
#pragma unroll
  for (int s = 0; s < 8; ++s) sm += expf(loc[s] - m);
  red[tid] = sm; __syncthreads();
  for (int off = 512; off > 0; off >>= 1) {
    if (tid < off) red[tid] += red[tid + off];
    __syncthreads();
  }
  float Z = red[0];
#pragma unroll
  for (int s = 0; s < 8; ++s)
    out[1 + tid + s * 1024] = expf(loc[s] - m) / Z;
}

// ============================================================
__global__ __launch_bounds__(256) void z_partial(
    const float* __restrict__ aw, const float* __restrict__ query,
    float* __restrict__ zpart)
{
  const int g = blockIdx.x, t = threadIdx.x;
  float a0 = 0.f, a1 = 0.f;
  for (int r = 0; r < 64; ++r) {
    int n = g * 64 + r;
    float w = aw[n];
    const float* q = query + (size_t)n * HDIM;
    a0 = fmaf(w, q[t],       a0);
    a1 = fmaf(w, q[t + 256], a1);
  }
  zpart[(size_t)g * HDIM + t]       = a0;
  zpart[(size_t)g * HDIM + t + 256] = a1;
}

__global__ __launch_bounds__(512) void finalize(
    const float* __restrict__ zpart, const float* __restrict__ cls_w,
    const float* __restrict__ cls_b, float* __restrict__ out)
{
  __shared__ float red[512];
  const int t = threadIdx.x;
  float s = 0.f;
  for (int g = 0; g < 128; ++g) s += zpart[(size_t)g * HDIM + t];
  red[t] = s * cls_w[t];
  __syncthreads();
  for (int off = 256; off > 0; off >>= 1) {
    if (t < off) red[t] += red[t + off];
    __syncthreads();
  }
  if (t == 0) out[0] = red[0] + cls_b[0];
}

// ============================================================
extern "C" void kernel_launch(void* const* d_in, const int* in_sizes, int n_in,
                              void* d_out, int out_size, void* d_ws, size_t ws_size,
                              hipStream_t stream) {
  (void)in_sizes; (void)n_in; (void)out_size; (void)ws_size;
  const float* x_q   = (const float*)d_in[0];
  const float* x_k   = (const float*)d_in[1];
  const float* WQ_w  = (const float*)d_in[2];
  const float* WQ_b  = (const float*)d_in[3];
  const float* WK_w  = (const float*)d_in[4];
  const float* WK_b  = (const float*)d_in[5];
  const float* WA_w  = (const float*)d_in[6];
  const float* WA_b  = (const float*)d_in[7];
  const float* cls_w = (const float*)d_in[8];
  const float* cls_b = (const float*)d_in[9];
  float* out = (float*)d_out;
  char* base = (char*)d_ws;

  // workspace layout (bytes), total ~82.4 MB
  float* query = (float*)(base);                          // 16 MB fp32
  u16* qn_hi   = (u16*)(base + (size_t)16 * (1u << 20));  // 8 MB
  u16* qn_lo   = (u16*)(base + (size_t)24 * (1u << 20));  // 8 MB
  u16* kn_hi   = (u16*)(base + (size_t)32 * (1u << 20));  // 8 MB
  u16* kn_lo   = (u16*)(base + (size_t)40 * (1u << 20));  // 8 MB
  float* keyt  = (float*)(base + (size_t)48 * (1u << 20));// 16 MB (dead before Ach use)
  float* Ach   = (float*)(base + (size_t)48 * (1u << 20));// 32 MB chunk of A
  u16* wt_hi   = (u16*)(base + (size_t)80 * (1u << 20));  // 1 MB
  u16* wt_lo   = (u16*)(base + (size_t)81 * (1u << 20));  // 1 MB
  float* Acmb  = (float*)(base + (size_t)82 * (1u << 20));// 32 KB
  float* zpart = (float*)(base + (size_t)82 * (1u << 20) + 65536); // 256 KB

  dim3 b256(256);
  // --- query = tanh(x_q @ WQ + b) via split-bf16 MFMA ---
  wt_cast<<<dim3(16, 32), b256, 0, stream>>>(WQ_w, wt_hi, wt_lo);
  gemm_f32a_hl_tanh<<<dim3(HDIM / 128, NTOK / 128), b256, 0, stream>>>(
      x_q, wt_hi, wt_lo, WQ_b, query, DIM, HDIM);
  rownorm_split<<<NTOK / 4, b256, 0, stream>>>(query, qn_hi, qn_lo);
  // --- keyt = tanh(x_k @ WK + b) ---
  wt_cast<<<dim3(16, 32), b256, 0, stream>>>(WK_w, wt_hi, wt_lo);
  gemm_f32a_hl_tanh<<<dim3(HDIM / 128, NTOK / 128), b256, 0, stream>>>(
      x_k, wt_hi, wt_lo, WK_b, keyt, DIM, HDIM);
  rownorm_split<<<NTOK / 4, b256, 0, stream>>>(keyt, kn_hi, kn_lo);
  // --- A = qn . kn^T in row chunks (split-bf16 MFMA), fused top-100 -> Acmb ---
  for (int c = 0; c < NTOK / CHUNK; ++c) {
    gemm_hl_nt<<<dim3(NTOK / 128, CHUNK / 128), b256, 0, stream>>>(
        qn_hi + (size_t)c * CHUNK * HDIM, qn_lo + (size_t)c * CHUNK * HDIM,
        kn_hi, kn_lo, Ach, HDIM, NTOK);
    topk_acmb<<<CHUNK, dim3(512), 0, stream>>>(Ach, WA_w, WA_b, Acmb, c * CHUNK);
  }
  // --- threshold + softmax -> Aw (out[1..8192]) ---
  thr_softmax<<<1, dim3(1024), 0, stream>>>(Acmb, out);
  // --- z = Aw @ query ; Y = z.cls_w + cls_b -> out[0] ---
  z_partial<<<128, b256, 0, stream>>>(out + 1, query, zpart);
  finalize<<<1, dim3(512), 0, stream>>>(zpart, cls_w, cls_b, out);
}

// Round 4
// 748.647 us; speedup vs baseline: 2.0920x; 1.0234x over previous
//
#include <hip/hip_runtime.h>
#include <hip/hip_bf16.h>
#include <math.h>

#define NTOK 8192
#define DIM  1024
#define HDIM 512
#define KTOP 100
#define CHUNK 1024
#define KTH_RANK 2457   // threshold = 2457th-largest of Acmb == sort_asc[5735]

typedef float f32x4 __attribute__((ext_vector_type(4)));
typedef short bf16x8 __attribute__((ext_vector_type(8)));
typedef unsigned int u32;
typedef unsigned short u16;

// ---- monotone float<->uint key (order-preserving) ----
__device__ __forceinline__ unsigned key_of(float f) {
  unsigned u = __float_as_uint(f);
  return (u & 0x80000000u) ? ~u : (u | 0x80000000u);
}
__device__ __forceinline__ float float_of_key(unsigned key) {
  unsigned u = (key & 0x80000000u) ? (key ^ 0x80000000u) : ~key;
  return __uint_as_float(u);
}
// ---- bf16 round-to-nearest-even helpers ----
__device__ __forceinline__ u16 bf16_rn(float x) {
  unsigned u = __float_as_uint(x);
  return (u16)((u + 0x7FFFu + ((u >> 16) & 1u)) >> 16);
}
__device__ __forceinline__ float bf16f(u16 h) {
  return __uint_as_float(((unsigned)h) << 16);
}
// ---- async global->LDS 16B ----
__device__ __forceinline__ void gload16(const void* gptr, void* lptr) {
  __builtin_amdgcn_global_load_lds(
      (const __attribute__((address_space(1))) u32*)gptr,
      (__attribute__((address_space(3))) u32*)lptr, 16, 0, 0);
}

// ============================================================
// Unified split-bf16 NT GEMM.  C = (Ahi+Alo).(Bhi+Blo)^T  (both k-contig)
// Tile BM x 128, BK=64, 512 threads (8 waves, 2x4), wave tile (FM*16) x 32.
// LDS XOR-swizzle: byte ^= ((row&7)<<4), applied on BOTH the pre-swizzled
// global source (linear gload_lds dest) and the frag reads -> conflict-free.
// MODE 0: C fp32.  MODE 1: tanh(C+bias) fp32.  MODE 2: tanh(C+bias) -> hi/lo.
// ============================================================
template<int MODE, int FM>
__global__ __launch_bounds__(512, 4) void gemm_hl(
    const u16* __restrict__ Ahi, const u16* __restrict__ Alo,
    const u16* __restrict__ Bhi, const u16* __restrict__ Blo,
    float* __restrict__ Cf, u16* __restrict__ Chi, u16* __restrict__ Clo,
    const float* __restrict__ bias, int K, int ldc)
{
  constexpr int BM = FM * 32;
  __shared__ __align__(16) short sAh[BM * 64], sAl[BM * 64];
  __shared__ __align__(16) short sBh[128 * 64], sBl[128 * 64];
  const int tid = threadIdx.x;
  const int lane = tid & 63, wave = tid >> 6;
  const int wm = wave >> 2, wn = wave & 3;          // 2 x 4 wave grid
  const int bm = blockIdx.y * BM, bn = blockIdx.x * 128;
  f32x4 acc[FM][2] = {};

  // swizzled per-lane source k-offset (shorts): ((l&7)*8) ^ ((l>>3)<<3)
  const int selem = ((lane & 7) * 8) ^ ((lane >> 3) << 3);
  constexpr int NROWIT = (2 * BM + 256) / 64;       // staging row-iterations

  for (int k0 = 0; k0 < K; k0 += 64) {
    // ---- stage 2*(BM+128) rows of 128B; 8 waves x 8 rows per iter ----
#pragma unroll
    for (int j = 0; j < NROWIT; ++j) {
      int gb = j * 64 + wave * 8;                   // wave-uniform row base
      const u16* gp; short* lp; int r0; size_t grb;
      if (gb < BM)            { gp = Ahi; lp = sAh; r0 = gb;            grb = bm; }
      else if (gb < 2*BM)     { gp = Alo; lp = sAl; r0 = gb - BM;       grb = bm; }
      else if (gb < 2*BM+128) { gp = Bhi; lp = sBh; r0 = gb - 2*BM;     grb = bn; }
      else                    { gp = Blo; lp = sBl; r0 = gb - 2*BM-128; grb = bn; }
      int row = r0 + (lane >> 3);
      gload16(gp + (grb + row) * (size_t)K + k0 + selem, lp + r0 * 64);
    }
    __syncthreads();   // drains vmcnt(0) then barrier

    // ---- MFMA: 2 k-subtiles of 32 ----
#pragma unroll
    for (int kk = 0; kk < 2; ++kk) {
      const int fb = (kk * 32 + (lane >> 4) * 8) ^ ((lane & 7) << 3);
      bf16x8 ah[FM], al[FM];
#pragma unroll
      for (int m = 0; m < FM; ++m) {
        int off = (wm * (FM * 16) + m * 16 + (lane & 15)) * 64 + fb;
        ah[m] = *(const bf16x8*)&sAh[off];
        al[m] = *(const bf16x8*)&sAl[off];
      }
#pragma unroll
      for (int n = 0; n < 2; ++n) {
        int off = (wn * 32 + n * 16 + (lane & 15)) * 64 + fb;
        bf16x8 bh = *(const bf16x8*)&sBh[off];
        bf16x8 bl = *(const bf16x8*)&sBl[off];
#pragma unroll
        for (int m = 0; m < FM; ++m) {
          acc[m][n] = __builtin_amdgcn_mfma_f32_16x16x32_bf16(ah[m], bh, acc[m][n], 0, 0, 0);
          acc[m][n] = __builtin_amdgcn_mfma_f32_16x16x32_bf16(ah[m], bl, acc[m][n], 0, 0, 0);
          acc[m][n] = __builtin_amdgcn_mfma_f32_16x16x32_bf16(al[m], bh, acc[m][n], 0, 0, 0);
        }
      }
    }
    __syncthreads();
  }

  // ---- epilogue ----
#pragma unroll
  for (int m = 0; m < FM; ++m) {
    int rbase = bm + wm * (FM * 16) + m * 16 + (lane >> 4) * 4;
#pragma unroll
    for (int n = 0; n < 2; ++n) {
      int col = bn + wn * 32 + n * 16 + (lane & 15);
#pragma unroll
      for (int r = 0; r < 4; ++r) {
        size_t oidx = (size_t)(rbase + r) * ldc + col;
        if (MODE == 0) {
          Cf[oidx] = acc[m][n][r];
        } else if (MODE == 1) {
          Cf[oidx] = tanhf(acc[m][n][r] + bias[col]);
        } else {
          float t = tanhf(acc[m][n][r] + bias[col]);
          u16 h = bf16_rn(t);
          Chi[oidx] = h;
          Clo[oidx] = bf16_rn(t - bf16f(h));
        }
      }
    }
  }
}

// ============================================================
// x [8192x1024] fp32 -> hi/lo bf16 (memory-bound)
// ============================================================
__global__ __launch_bounds__(256) void xsplit(
    const float* __restrict__ x, u16* __restrict__ hi, u16* __restrict__ lo)
{
  for (int i = blockIdx.x * 256 + threadIdx.x; i < NTOK * DIM / 4; i += gridDim.x * 256) {
    float4 v = ((const float4*)x)[i];
    ushort4 h, l;
    h.x = bf16_rn(v.x); l.x = bf16_rn(v.x - bf16f(h.x));
    h.y = bf16_rn(v.y); l.y = bf16_rn(v.y - bf16f(h.y));
    h.z = bf16_rn(v.z); l.z = bf16_rn(v.z - bf16f(h.z));
    h.w = bf16_rn(v.w); l.w = bf16_rn(v.w - bf16f(h.w));
    ((ushort4*)hi)[i] = h;
    ((ushort4*)lo)[i] = l;
  }
}

// ============================================================
// W [K=1024][N=512] fp32 -> WT hi/lo [512][1024] bf16 (tiled transpose)
// ============================================================
__global__ __launch_bounds__(256) void wt_cast(
    const float* __restrict__ W, u16* __restrict__ Thi, u16* __restrict__ Tlo)
{
  __shared__ float t[32][33];
  const int bx = blockIdx.x, by = blockIdx.y;
  const int r = threadIdx.x >> 5, c = threadIdx.x & 31;
#pragma unroll
  for (int i = 0; i < 4; ++i)
    t[r + i * 8][c] = W[(size_t)(by * 32 + r + i * 8) * HDIM + bx * 32 + c];
  __syncthreads();
#pragma unroll
  for (int i = 0; i < 4; ++i) {
    int n = bx * 32 + r + i * 8, k = by * 32 + c;
    float v = t[c][r + i * 8];
    u16 h = bf16_rn(v);
    Thi[(size_t)n * DIM + k] = h;
    Tlo[(size_t)n * DIM + k] = bf16_rn(v - bf16f(h));
  }
}

// ============================================================
// Row L2-normalize fp32 src -> hi/lo bf16 (one wave per row)
// ============================================================
__global__ __launch_bounds__(256) void rownorm_split(
    const float* __restrict__ src, u16* __restrict__ hi, u16* __restrict__ lo)
{
  const int lane = threadIdx.x & 63;
  const int row = blockIdx.x * 4 + (threadIdx.x >> 6);
  const float* s = src + (size_t)row * HDIM;
  float4 v0 = *(const float4*)&s[lane * 8];
  float4 v1 = *(const float4*)&s[lane * 8 + 4];
  float ss = v0.x*v0.x + v0.y*v0.y + v0.z*v0.z + v0.w*v0.w
           + v1.x*v1.x + v1.y*v1.y + v1.z*v1.z + v1.w*v1.w;
#pragma unroll
  for (int off = 32; off > 0; off >>= 1) ss += __shfl_xor(ss, off);
  float sc = 1.0f / fmaxf(sqrtf(ss), 1e-12f);
  float q[8] = {v0.x*sc, v0.y*sc, v0.z*sc, v0.w*sc, v1.x*sc, v1.y*sc, v1.z*sc, v1.w*sc};
  u16 hh[8], ll[8];
#pragma unroll
  for (int j = 0; j < 8; ++j) { hh[j] = bf16_rn(q[j]); ll[j] = bf16_rn(q[j] - bf16f(hh[j])); }
  *(ushort4*)&hi[(size_t)row * HDIM + lane * 8]     = make_ushort4(hh[0], hh[1], hh[2], hh[3]);
  *(ushort4*)&hi[(size_t)row * HDIM + lane * 8 + 4] = make_ushort4(hh[4], hh[5], hh[6], hh[7]);
  *(ushort4*)&lo[(size_t)row * HDIM + lane * 8]     = make_ushort4(ll[0], ll[1], ll[2], ll[3]);
  *(ushort4*)&lo[(size_t)row * HDIM + lane * 8 + 4] = make_ushort4(ll[4], ll[5], ll[6], ll[7]);
}

// ============================================================
// In-place row L2-normalize of a hi/lo bf16 pair (one wave per row).
// Safe: each thread reads then rewrites only its own addresses.
// ============================================================
__global__ __launch_bounds__(256) void rownorm_hl(
    u16* __restrict__ hi, u16* __restrict__ lo)
{
  const int lane = threadIdx.x & 63;
  const int row = blockIdx.x * 4 + (threadIdx.x >> 6);
  size_t base = (size_t)row * HDIM + lane * 8;
  ushort4 h0 = *(ushort4*)&hi[base],     h1 = *(ushort4*)&hi[base + 4];
  ushort4 l0 = *(ushort4*)&lo[base],     l1 = *(ushort4*)&lo[base + 4];
  float f[8] = {bf16f(h0.x)+bf16f(l0.x), bf16f(h0.y)+bf16f(l0.y),
                bf16f(h0.z)+bf16f(l0.z), bf16f(h0.w)+bf16f(l0.w),
                bf16f(h1.x)+bf16f(l1.x), bf16f(h1.y)+bf16f(l1.y),
                bf16f(h1.z)+bf16f(l1.z), bf16f(h1.w)+bf16f(l1.w)};
  float ss = 0.f;
#pragma unroll
  for (int j = 0; j < 8; ++j) ss += f[j] * f[j];
#pragma unroll
  for (int off = 32; off > 0; off >>= 1) ss += __shfl_xor(ss, off);
  float sc = 1.0f / fmaxf(sqrtf(ss), 1e-12f);
  u16 hh[8], ll[8];
#pragma unroll
  for (int j = 0; j < 8; ++j) {
    float q = f[j] * sc;
    hh[j] = bf16_rn(q); ll[j] = bf16_rn(q - bf16f(hh[j]));
  }
  *(ushort4*)&hi[base]     = make_ushort4(hh[0], hh[1], hh[2], hh[3]);
  *(ushort4*)&hi[base + 4] = make_ushort4(hh[4], hh[5], hh[6], hh[7]);
  *(ushort4*)&lo[base]     = make_ushort4(ll[0], ll[1], ll[2], ll[3]);
  *(ushort4*)&lo[base + 4] = make_ushort4(ll[4], ll[5], ll[6], ll[7]);
}

// ============================================================
// Per-row exact top-100: top-byte radix pass over full row, then compact
// candidates (keys with top byte >= boundary digit) and finish passes 2..0,
// collect, bitonic-sort, dot with WA.  One block (1024 thr) per row.
// ============================================================
__global__ __launch_bounds__(1024) void topk_acmb(
    const float* __restrict__ Arows, const float* __restrict__ WA_w,
    const float* __restrict__ WA_b, float* __restrict__ Acmb, int row_base)
{
  __shared__ unsigned rowk[NTOK];       // 32 KB
  __shared__ unsigned cmpk[4096];       // 16 KB candidate compaction
  __shared__ unsigned hist[256];
  __shared__ unsigned sufs[256];
  __shared__ unsigned cand[128];
  __shared__ float red[128];
  __shared__ unsigned s_prefix, s_need, s_ncand, s_cc, s_cg, s_ce;

  const int tid = threadIdx.x;
  const float4* src = (const float4*)(Arows + (size_t)blockIdx.x * NTOK);
#pragma unroll
  for (int it = 0; it < 2; ++it) {
    int i = tid + it * 1024;
    float4 v = src[i];
    *(uint4*)&rowk[i * 4] =
        make_uint4(key_of(v.x), key_of(v.y), key_of(v.z), key_of(v.w));
  }
  if (tid == 0) { s_prefix = 0u; s_need = KTOP; s_ncand = 0u; s_cc = 0u; s_cg = 0u; s_ce = 0u; }
  if (tid < 256) hist[tid] = 0u;
  __syncthreads();

  // ---- pass 3: top byte over full row ----
#pragma unroll
  for (int it = 0; it < 8; ++it)
    atomicAdd(&hist[rowk[tid + it * 1024] >> 24], 1u);
  __syncthreads();
  if (tid < 256) sufs[tid] = hist[tid];
  __syncthreads();
  for (int off = 1; off < 256; off <<= 1) {
    unsigned add = 0u;
    if (tid < 256 && tid + off < 256) add = sufs[tid + off];
    __syncthreads();
    if (tid < 256) sufs[tid] += add;
    __syncthreads();
  }
  if (tid < 256) {
    unsigned above = (tid == 255) ? 0u : sufs[tid + 1];
    if (sufs[tid] >= KTOP && above < KTOP) {
      s_prefix = (unsigned)tid << 24;
      s_need   = KTOP - above;
      s_ncand  = sufs[tid];        // all keys with top byte >= tid
    }
  }
  __syncthreads();
  const unsigned d3 = s_prefix >> 24;
  const unsigned ncand = s_ncand;
  const bool compact = (ncand <= 4096u);

  // ---- compact candidates ----
  if (compact) {
#pragma unroll
    for (int it = 0; it < 8; ++it) {
      unsigned key = rowk[tid + it * 1024];
      if ((key >> 24) >= d3) cmpk[atomicAdd(&s_cc, 1u)] = key;
    }
  }
  __syncthreads();

  // ---- passes 2..0 over candidates (or full row as fallback) ----
  for (int pass = 2; pass >= 0; --pass) {
    if (tid < 256) hist[tid] = 0u;
    __syncthreads();
    unsigned pref  = s_prefix;
    unsigned pmask = 0xFFFFFFFFu << ((pass + 1) * 8);
    if (compact) {
      for (int i = tid; i < (int)ncand; i += 1024) {
        unsigned key = cmpk[i];
        if ((key & pmask) == pref)
          atomicAdd(&hist[(key >> (pass * 8)) & 255u], 1u);
      }
    } else {
      for (int it = 0; it < 8; ++it) {
        unsigned key = rowk[tid + it * 1024];
        if ((key & pmask) == pref)
          atomicAdd(&hist[(key >> (pass * 8)) & 255u], 1u);
      }
    }
    __syncthreads();
    if (tid < 256) sufs[tid] = hist[tid];
    __syncthreads();
    for (int off = 1; off < 256; off <<= 1) {
      unsigned add = 0u;
      if (tid < 256 && tid + off < 256) add = sufs[tid + off];
      __syncthreads();
      if (tid < 256) sufs[tid] += add;
      __syncthreads();
    }
    unsigned need = s_need;
    __syncthreads();
    if (tid < 256) {
      unsigned above = (tid == 255) ? 0u : sufs[tid + 1];
      if (sufs[tid] >= need && above < need) {
        s_prefix = pref | ((unsigned)tid << (pass * 8));
        s_need   = need - above;
      }
    }
    __syncthreads();
  }
  const unsigned kth = s_prefix, needEq = s_need;

  // ---- collect: strictly-greater then equals ----
  if (tid < 128) cand[tid] = 0u;   // key 0 < any real key, sinks to front
  __syncthreads();
  if (compact) {
    for (int i = tid; i < (int)ncand; i += 1024) {
      unsigned key = cmpk[i];
      if (key > kth) cand[atomicAdd(&s_cg, 1u)] = key;
    }
  } else {
    for (int it = 0; it < 8; ++it) {
      unsigned key = rowk[tid + it * 1024];
      if (key > kth) cand[atomicAdd(&s_cg, 1u)] = key;
    }
  }
  __syncthreads();
  const unsigned nAbove = s_cg;
  if (compact) {
    for (int i = tid; i < (int)ncand; i += 1024) {
      unsigned key = cmpk[i];
      if (key == kth) {
        unsigned p = atomicAdd(&s_ce, 1u);
        if (p < needEq) cand[nAbove + p] = key;
      }
    }
  } else {
    for (int it = 0; it < 8; ++it) {
      unsigned key = rowk[tid + it * 1024];
      if (key == kth) {
        unsigned p = atomicAdd(&s_ce, 1u);
        if (p < needEq) cand[nAbove + p] = key;
      }
    }
  }
  __syncthreads();

  // ---- bitonic sort 128 ascending ----
  for (int k = 2; k <= 128; k <<= 1)
    for (int j = k >> 1; j > 0; j >>= 1) {
      if (tid < 128) {
        int i = tid, ixj = i ^ j;
        if (ixj > i) {
          unsigned a = cand[i], b = cand[ixj];
          if ((a > b) == ((i & k) == 0)) { cand[i] = b; cand[ixj] = a; }
        }
      }
      __syncthreads();
    }

  // ---- Acmb = -(sum A1*w1 + A1^2*w2 + b) ----
  float term = 0.0f;
  if (tid < KTOP) {
    float a1 = float_of_key(cand[28 + tid]);
    term = a1 * WA_w[tid] + a1 * a1 * WA_w[KTOP + tid];
  }
  if (tid < 128) red[tid] = term;
  __syncthreads();
  for (int off = 64; off > 0; off >>= 1) {
    if (tid < off) red[tid] += red[tid + off];
    __syncthreads();
  }
  if (tid == 0) Acmb[row_base + (int)blockIdx.x] = -(red[0] + WA_b[0]);
}

// ============================================================
// Threshold (rank select) + softmax over N -> Aw in out[1..N]
// ============================================================
__global__ __launch_bounds__(1024) void thr_softmax(
    const float* __restrict__ Acmb, float* __restrict__ out)
{
  __shared__ float vals[NTOK];
  __shared__ unsigned hist[256];
  __shared__ unsigned sufs[256];
  __shared__ float red[1024];
  __shared__ unsigned s_prefix, s_need;
  const int tid = threadIdx.x;
#pragma unroll
  for (int s = 0; s < 8; ++s) vals[tid + s * 1024] = Acmb[tid + s * 1024];
  if (tid == 0) { s_prefix = 0u; s_need = KTH_RANK; }
  __syncthreads();

  for (int pass = 3; pass >= 0; --pass) {
    if (tid < 256) hist[tid] = 0u;
    __syncthreads();
    unsigned pref  = s_prefix;
    unsigned pmask = (pass == 3) ? 0u : (0xFFFFFFFFu << ((pass + 1) * 8));
#pragma unroll
    for (int s = 0; s < 8; ++s) {
      unsigned key = key_of(vals[tid + s * 1024]);
      if ((key & pmask) == pref)
        atomicAdd(&hist[(key >> (pass * 8)) & 255u], 1u);
    }
    __syncthreads();
    if (tid < 256) sufs[tid] = hist[tid];
    __syncthreads();
    for (int off = 1; off < 256; off <<= 1) {
      unsigned add = 0u;
      if (tid < 256 && tid + off < 256) add = sufs[tid + off];
      __syncthreads();
      if (tid < 256) sufs[tid] += add;
      __syncthreads();
    }
    unsigned need = s_need;
    __syncthreads();
    if (tid < 256) {
      unsigned above = (tid == 255) ? 0u : sufs[tid + 1];
      if (sufs[tid] >= need && above < need) {
        s_prefix = pref | ((unsigned)tid << (pass * 8));
        s_need   = need - above;
      }
    }
    __syncthreads();
  }
  const float thre = float_of_key(s_prefix);

  float loc[8]; float mx = -1e30f;
#pragma unroll
  for (int s = 0; s < 8; ++s) {
    float v = vals[tid + s * 1024];
    v = (v > thre) ? v : 0.0f;
    loc[s] = v; mx = fmaxf(mx, v);
  }
  red[tid] = mx; __syncthreads();
  for (int off = 512; off > 0; off >>= 1) {
    if (tid < off) red[tid] = fmaxf(red[tid], red[tid + off]);
    __syncthreads();
  }
  float m = red[0]; __syncthreads();
  float sm = 0.0f;
#pragma unroll
  for (int s = 0; s < 8; ++s) sm += expf(loc[s] - m);
  red[tid] = sm; __syncthreads();
  for (int off = 512; off > 0; off >>= 1) {
    if (tid < off) red[tid] += red[tid + off];
    __syncthreads();
  }
  float Z = red[0];
#pragma unroll
  for (int s = 0; s < 8; ++s)
    out[1 + tid + s * 1024] = expf(loc[s] - m) / Z;
}

// ============================================================
__global__ __launch_bounds__(256) void z_partial(
    const float* __restrict__ aw, const float* __restrict__ query,
    float* __restrict__ zpart)
{
  const int g = blockIdx.x, t = threadIdx.x;
  float a0 = 0.f, a1 = 0.f;
  for (int r = 0; r < 64; ++r) {
    int n = g * 64 + r;
    float w = aw[n];
    const float* q = query + (size_t)n * HDIM;
    a0 = fmaf(w, q[t],       a0);
    a1 = fmaf(w, q[t + 256], a1);
  }
  zpart[(size_t)g * HDIM + t]       = a0;
  zpart[(size_t)g * HDIM + t + 256] = a1;
}

__global__ __launch_bounds__(512) void finalize(
    const float* __restrict__ zpart, const float* __restrict__ cls_w,
    const float* __restrict__ cls_b, float* __restrict__ out)
{
  __shared__ float red[512];
  const int t = threadIdx.x;
  float s = 0.f;
  for (int g = 0; g < 128; ++g) s += zpart[(size_t)g * HDIM + t];
  red[t] = s * cls_w[t];
  __syncthreads();
  for (int off = 256; off > 0; off >>= 1) {
    if (t < off) red[t] += red[t + off];
    __syncthreads();
  }
  if (t == 0) out[0] = red[0] + cls_b[0];
}

// ============================================================
extern "C" void kernel_launch(void* const* d_in, const int* in_sizes, int n_in,
                              void* d_out, int out_size, void* d_ws, size_t ws_size,
                              hipStream_t stream) {
  (void)in_sizes; (void)n_in; (void)out_size; (void)ws_size;
  const float* x_q   = (const float*)d_in[0];
  const float* x_k   = (const float*)d_in[1];
  const float* WQ_w  = (const float*)d_in[2];
  const float* WQ_b  = (const float*)d_in[3];
  const float* WK_w  = (const float*)d_in[4];
  const float* WK_b  = (const float*)d_in[5];
  const float* WA_w  = (const float*)d_in[6];
  const float* WA_b  = (const float*)d_in[7];
  const float* cls_w = (const float*)d_in[8];
  const float* cls_b = (const float*)d_in[9];
  float* out = (float*)d_out;
  char* base = (char*)d_ws;
  const size_t MB = 1u << 20;

  float* query = (float*)(base);              // 0..16 MB fp32
  u16* qn_hi   = (u16*)(base + 16 * MB);      // 16..24
  u16* qn_lo   = (u16*)(base + 24 * MB);      // 24..32
  u16* kn_hi   = (u16*)(base + 32 * MB);      // 32..40
  u16* kn_lo   = (u16*)(base + 40 * MB);      // 40..48
  u16* xs_hi   = (u16*)(base + 48 * MB);      // 48..64 (dead after projections)
  u16* xs_lo   = (u16*)(base + 64 * MB);      // 64..80
  float* Ach   = (float*)(base + 48 * MB);    // 48..80 (A chunk, 32 MB)
  u16* wt_hi   = (u16*)(base + 80 * MB);      // 80..81
  u16* wt_lo   = (u16*)(base + 81 * MB);      // 81..82
  float* Acmb  = (float*)(base + 82 * MB);    // 32 KB
  float* zpart = (float*)(base + 82 * MB + 65536);  // 256 KB

  dim3 b256(256), b512(512);
  dim3 gproj(HDIM / 128, NTOK / 64);          // FM=2: 4 x 128 = 512 blocks
  dim3 gchunk(NTOK / 128, CHUNK / 128);       // FM=4: 64 x 8  = 512 blocks

  // --- query = tanh(x_q @ WQ + b) ---
  wt_cast<<<dim3(16, 32), b256, 0, stream>>>(WQ_w, wt_hi, wt_lo);
  xsplit<<<2048, b256, 0, stream>>>(x_q, xs_hi, xs_lo);
  gemm_hl<1, 2><<<gproj, b512, 0, stream>>>(xs_hi, xs_lo, wt_hi, wt_lo,
      query, nullptr, nullptr, WQ_b, DIM, HDIM);
  rownorm_split<<<NTOK / 4, b256, 0, stream>>>(query, qn_hi, qn_lo);
  // --- kn = normalize(tanh(x_k @ WK + b)) ---
  wt_cast<<<dim3(16, 32), b256, 0, stream>>>(WK_w, wt_hi, wt_lo);
  xsplit<<<2048, b256, 0, stream>>>(x_k, xs_hi, xs_lo);
  gemm_hl<2, 2><<<gproj, b512, 0, stream>>>(xs_hi, xs_lo, wt_hi, wt_lo,
      nullptr, kn_hi, kn_lo, WK_b, DIM, HDIM);
  rownorm_hl<<<NTOK / 4, b256, 0, stream>>>(kn_hi, kn_lo);
  // --- A chunks + fused exact top-100 -> Acmb ---
  for (int c = 0; c < NTOK / CHUNK; ++c) {
    gemm_hl<0, 4><<<gchunk, b512, 0, stream>>>(
        qn_hi + (size_t)c * CHUNK * HDIM, qn_lo + (size_t)c * CHUNK * HDIM,
        kn_hi, kn_lo, Ach, nullptr, nullptr, nullptr, HDIM, NTOK);
    topk_acmb<<<CHUNK, dim3(1024), 0, stream>>>(Ach, WA_w, WA_b, Acmb, c * CHUNK);
  }
  // --- threshold + softmax -> Aw ---
  thr_softmax<<<1, dim3(1024), 0, stream>>>(Acmb, out);
  // --- z = Aw @ query ; Y -> out[0] ---
  z_partial<<<128, b256, 0, stream>>>(out + 1, query, zpart);
  finalize<<<1, dim3(512), 0, stream>>>(zpart, cls_w, cls_b, out);
}